// Round 1
// baseline (1867.431 us; speedup 1.0000x reference)
//
#include <hip/hip_runtime.h>

typedef __attribute__((ext_vector_type(8))) short short8;
typedef __attribute__((ext_vector_type(4))) float f32x4;

#define DEV static __device__ __forceinline__

typedef __attribute__((address_space(1))) void GVoid;
typedef __attribute__((address_space(3))) void LVoid;

DEV unsigned short f2bf(float f) {
  unsigned u = __builtin_bit_cast(unsigned, f);
  u += 0x7fffu + ((u >> 16) & 1u);   // RNE
  return (unsigned short)(u >> 16);
}
DEV float bf2f(unsigned short h) {
  unsigned u = ((unsigned)h) << 16;
  return __builtin_bit_cast(float, u);
}
DEV void cp16(void* lds_uniform_base, const void* gsrc) {
  // async global->LDS, 16B per lane; LDS dest = wave-uniform base + lane*16
  __builtin_amdgcn_global_load_lds((GVoid*)gsrc, (LVoid*)lds_uniform_base, 16, 0, 0);
}

// Bijective XCD-chunk swizzle: consecutive logical blocks (which share B-panels)
// land on the same XCD's L2. Requires nwg % 8 == 0 (true for all our grids).
DEV void xcd_remap(int& mb, int& nb) {
  const int gx = gridDim.x;
  const int p = blockIdx.x + gx * blockIdx.y;
  const int nwg = gx * gridDim.y;
  const int q = nwg >> 3;
  const int L = (p & 7) * q + (p >> 3);
  mb = L % gx;
  nb = L / gx;
}

// ---------------------------------------------------------------------------
// Setup: cast weights to bf16 (wqkv concat [768][256], conv perm [co][tap][ci],
// out_w [256][256]) + 256B zero page for conv SAME-padding staging.
// ---------------------------------------------------------------------------
__global__ __launch_bounds__(256) void setup_kernel(
    const float* __restrict__ wq, const float* __restrict__ wk, const float* __restrict__ wv,
    const float* __restrict__ lw, const float* __restrict__ ow,
    unsigned short* __restrict__ wqkvb, unsigned short* __restrict__ w2b,
    unsigned short* __restrict__ woutb, unsigned short* __restrict__ zp)
{
  int i = blockIdx.x * 256 + threadIdx.x;
  if (i < 196608) {
    float f = (i < 65536) ? wq[i] : (i < 131072) ? wk[i - 65536] : wv[i - 131072];
    wqkvb[i] = f2bf(f);
  } else if (i < 786432) {
    int j = i - 196608;
    int co = j / 2304;
    int r = j - co * 2304;
    int tap = r >> 8;
    int ci = r & 255;
    // local_w flat [co][ci][ky][kx] = (co*256+ci)*9 + tap
    w2b[j] = f2bf(lw[(co * 256 + ci) * 9 + tap]);
  } else if (i < 851968) {
    int j = i - 786432;
    woutb[j] = f2bf(ow[j]);
  } else if (i < 852096) {
    zp[i - 851968] = 0;
  }
}

// ---------------------------------------------------------------------------
// ChanLayerNorm -> xn bf16 in window-major layout [n'][256].
// Threads mapped in RASTER order so a wave's 64 lanes read 256 contiguous
// bytes per channel (fully-used cache lines); output index is window-major:
// n' = ((b*16+X)*16+Y)*64 + w1*8 + w2 ;  h=X*8+w1, w=Y*8+w2.
// ---------------------------------------------------------------------------
__global__ __launch_bounds__(256) void ln_kernel(
    const float* __restrict__ x, const float* __restrict__ gw,
    const float* __restrict__ bw, unsigned short* __restrict__ xn)
{
  const int t = threadIdx.x;
  const int p = blockIdx.x * 256 + t;   // raster pixel index within chunk
  const int b = p >> 14;
  const int pix = p & 16383;
  const int h = pix >> 7;
  const int w = pix & 127;
  const float* xp = x + ((size_t)b << 22) + pix;  // b*256*16384 + h*128 + w

  float sum = 0.f, ss = 0.f;
#pragma unroll 8
  for (int c = 0; c < 256; ++c) {
    float f = xp[(size_t)c << 14];
    sum += f;
    ss += f * f;
  }
  float mean = sum * (1.f / 256.f);
  float var = ss * (1.f / 256.f) - mean * mean;
  float inv = rsqrtf(var + 1e-5f);

  // window-major output position
  const int pw = ((b * 16 + (h >> 3)) * 16 + (w >> 3)) * 64 + (h & 7) * 8 + (w & 7);
  unsigned short* op = xn + (size_t)pw * 256;
#pragma unroll 2
  for (int c = 0; c < 256; c += 4) {
    float f0 = xp[(size_t)(c + 0) << 14];
    float f1 = xp[(size_t)(c + 1) << 14];
    float f2 = xp[(size_t)(c + 2) << 14];
    float f3 = xp[(size_t)(c + 3) << 14];
    float v0 = (f0 - mean) * inv * gw[c + 0] + bw[c + 0];
    float v1 = (f1 - mean) * inv * gw[c + 1] + bw[c + 1];
    float v2 = (f2 - mean) * inv * gw[c + 2] + bw[c + 2];
    float v3 = (f3 - mean) * inv * gw[c + 3] + bw[c + 3];
    unsigned long long pk = (unsigned long long)f2bf(v0) |
                            ((unsigned long long)f2bf(v1) << 16) |
                            ((unsigned long long)f2bf(v2) << 32) |
                            ((unsigned long long)f2bf(v3) << 48);
    *(unsigned long long*)(op + c) = pk;
  }
}

// ---------------------------------------------------------------------------
// Shared MFMA inner: 128x128 block tile, BK=64 (two 32-k steps), 4 waves 2x2.
// LDS tiles stored [16-dim][K] so fragment reads are ds_read_b128.
// ---------------------------------------------------------------------------
DEV void mfma_tile(const unsigned short* As, const unsigned short* Bs,
                   int wm, int wn, int l15, int quad, f32x4 (&acc)[4][4])
{
#pragma unroll
  for (int ks = 0; ks < 2; ++ks) {
    short8 a[4], b[4];
#pragma unroll
    for (int i = 0; i < 4; ++i)
      a[i] = *(const short8*)(As + (wm + i * 16 + l15) * 64 + ks * 32 + quad * 8);
#pragma unroll
    for (int j = 0; j < 4; ++j)
      b[j] = *(const short8*)(Bs + (wn + j * 16 + l15) * 64 + ks * 32 + quad * 8);
#pragma unroll
    for (int i = 0; i < 4; ++i)
#pragma unroll
      for (int j = 0; j < 4; ++j)
        acc[i][j] = __builtin_amdgcn_mfma_f32_16x16x32_bf16(a[i], b[j], acc[i][j], 0, 0, 0);
  }
}

// ---------------------------------------------------------------------------
// QKV projection: [768x256] @ xn[Nc x 256]^T -> q,k,v bf16 [n'][256]
// grid = (6 m-blocks, Nc/128 n-blocks), XCD-swizzled
// ---------------------------------------------------------------------------
__global__ __launch_bounds__(256) void qkv_gemm(
    const unsigned short* __restrict__ wqkvb, const unsigned short* __restrict__ xn,
    unsigned short* __restrict__ qb, unsigned short* __restrict__ kb,
    unsigned short* __restrict__ vb)
{
  __shared__ __align__(16) unsigned short As[128 * 64];
  __shared__ __align__(16) unsigned short Bs[128 * 64];
  const int tid = threadIdx.x;
  const int lane = tid & 63;
  const int wave = tid >> 6;
  const int l15 = lane & 15;
  const int quad = lane >> 4;
  const int wm = (wave >> 1) * 64;
  const int wn = (wave & 1) * 64;
  const int sub = tid & 7;
  const int row0 = tid >> 3;
  int mb, nb;
  xcd_remap(mb, nb);
  const int m0 = mb * 128;
  const int n0 = nb * 128;

  f32x4 acc[4][4];
  f32x4 zero = {0.f, 0.f, 0.f, 0.f};
#pragma unroll
  for (int i = 0; i < 4; ++i)
#pragma unroll
    for (int j = 0; j < 4; ++j) acc[i][j] = zero;

  for (int kt = 0; kt < 4; ++kt) {
    const int k0 = kt * 64;
#pragma unroll
    for (int it = 0; it < 4; ++it) {
      const int row = it * 32 + row0;
      cp16(As + (size_t)(it * 256 + wave * 64) * 8,
           wqkvb + (size_t)(m0 + row) * 256 + k0 + sub * 8);
      cp16(Bs + (size_t)(it * 256 + wave * 64) * 8,
           xn + (size_t)(n0 + row) * 256 + k0 + sub * 8);
    }
    __syncthreads();
    mfma_tile(As, Bs, wm, wn, l15, quad, acc);
    __syncthreads();
  }

  unsigned short* ob = (m0 < 256) ? qb : (m0 < 512) ? kb : vb;
  const int chb = (m0 & 255) + wm;
#pragma unroll
  for (int i = 0; i < 4; ++i) {
    const int ch = chb + i * 16 + quad * 4;
#pragma unroll
    for (int j = 0; j < 4; ++j) {
      const int n = n0 + wn + j * 16 + l15;
      unsigned long long pk = (unsigned long long)f2bf(acc[i][j][0]) |
                              ((unsigned long long)f2bf(acc[i][j][1]) << 16) |
                              ((unsigned long long)f2bf(acc[i][j][2]) << 32) |
                              ((unsigned long long)f2bf(acc[i][j][3]) << 48);
      *(unsigned long long*)(ob + (size_t)n * 256 + ch) = pk;
    }
  }
}

// ---------------------------------------------------------------------------
// Windowed attention, fp32 VALU. Block = (window, head-pair), 128 threads.
// Thread = (token, head). k/v staged to LDS as float4 (padded leading dim to
// break 128B-stride write conflicts); softmax per-thread.
// ---------------------------------------------------------------------------
__global__ __launch_bounds__(128) void attn_kernel(
    const unsigned short* __restrict__ qb, const unsigned short* __restrict__ kb,
    const unsigned short* __restrict__ vb, unsigned short* __restrict__ attnb)
{
  __shared__ float4 ks4[2][64][9];   // [8 used, +1 pad]
  __shared__ float4 vs4[2][64][9];
  const int tid = threadIdx.x;
  const int tok = tid & 63;
  const int hs = tid >> 6;  // 0..1
  const int win = blockIdx.x >> 2;
  const int head = (blockIdx.x & 3) * 2 + hs;
  const size_t base = (size_t)(win * 64 + tok) * 256 + head * 32;

  float qf[32];
  {
    const uint4* qp4 = (const uint4*)(qb + base);
    const uint4* kp4 = (const uint4*)(kb + base);
    const uint4* vp4 = (const uint4*)(vb + base);
#pragma unroll
    for (int i = 0; i < 4; ++i) {
      uint4 u = qp4[i];
      qf[8 * i + 0] = bf2f((unsigned short)(u.x & 0xffff));
      qf[8 * i + 1] = bf2f((unsigned short)(u.x >> 16));
      qf[8 * i + 2] = bf2f((unsigned short)(u.y & 0xffff));
      qf[8 * i + 3] = bf2f((unsigned short)(u.y >> 16));
      qf[8 * i + 4] = bf2f((unsigned short)(u.z & 0xffff));
      qf[8 * i + 5] = bf2f((unsigned short)(u.z >> 16));
      qf[8 * i + 6] = bf2f((unsigned short)(u.w & 0xffff));
      qf[8 * i + 7] = bf2f((unsigned short)(u.w >> 16));
    }
#pragma unroll
    for (int i = 0; i < 4; ++i) {
      uint4 u = kp4[i];
      float4 f0, f1;
      f0.x = bf2f((unsigned short)(u.x & 0xffff));
      f0.y = bf2f((unsigned short)(u.x >> 16));
      f0.z = bf2f((unsigned short)(u.y & 0xffff));
      f0.w = bf2f((unsigned short)(u.y >> 16));
      f1.x = bf2f((unsigned short)(u.z & 0xffff));
      f1.y = bf2f((unsigned short)(u.z >> 16));
      f1.z = bf2f((unsigned short)(u.w & 0xffff));
      f1.w = bf2f((unsigned short)(u.w >> 16));
      ks4[hs][tok][2 * i] = f0;
      ks4[hs][tok][2 * i + 1] = f1;
      uint4 v = vp4[i];
      float4 g0, g1;
      g0.x = bf2f((unsigned short)(v.x & 0xffff));
      g0.y = bf2f((unsigned short)(v.x >> 16));
      g0.z = bf2f((unsigned short)(v.y & 0xffff));
      g0.w = bf2f((unsigned short)(v.y >> 16));
      g1.x = bf2f((unsigned short)(v.z & 0xffff));
      g1.y = bf2f((unsigned short)(v.z >> 16));
      g1.z = bf2f((unsigned short)(v.w & 0xffff));
      g1.w = bf2f((unsigned short)(v.w >> 16));
      vs4[hs][tok][2 * i] = g0;
      vs4[hs][tok][2 * i + 1] = g1;
    }
  }
  __syncthreads();

  float dots[64];
#pragma unroll
  for (int j = 0; j < 64; ++j) {
    float d = 0.f;
#pragma unroll
    for (int c4 = 0; c4 < 8; ++c4) {
      float4 kk = ks4[hs][j][c4];
      d += qf[4 * c4 + 0] * kk.x + qf[4 * c4 + 1] * kk.y +
           qf[4 * c4 + 2] * kk.z + qf[4 * c4 + 3] * kk.w;
    }
    dots[j] = d * 0.17677669529663688f;  // 32^-0.5
  }
  float mx = -1e30f;
#pragma unroll
  for (int j = 0; j < 64; ++j) mx = fmaxf(mx, dots[j]);
  float s = 0.f;
#pragma unroll
  for (int j = 0; j < 64; ++j) {
    float e = __expf(dots[j] - mx);
    dots[j] = e;
    s += e;
  }
  const float rs = 1.f / s;

  float of[32];
#pragma unroll
  for (int c = 0; c < 32; ++c) of[c] = 0.f;
#pragma unroll
  for (int j = 0; j < 64; ++j) {
    const float p = dots[j];
#pragma unroll
    for (int c4 = 0; c4 < 8; ++c4) {
      float4 vv = vs4[hs][j][c4];
      of[4 * c4 + 0] += p * vv.x;
      of[4 * c4 + 1] += p * vv.y;
      of[4 * c4 + 2] += p * vv.z;
      of[4 * c4 + 3] += p * vv.w;
    }
  }
  uint4* op4 = (uint4*)(attnb + base);
#pragma unroll
  for (int i = 0; i < 4; ++i) {
    uint4 o;
    o.x = (unsigned)f2bf(of[8 * i + 0] * rs) | ((unsigned)f2bf(of[8 * i + 1] * rs) << 16);
    o.y = (unsigned)f2bf(of[8 * i + 2] * rs) | ((unsigned)f2bf(of[8 * i + 3] * rs) << 16);
    o.z = (unsigned)f2bf(of[8 * i + 4] * rs) | ((unsigned)f2bf(of[8 * i + 5] * rs) << 16);
    o.w = (unsigned)f2bf(of[8 * i + 6] * rs) | ((unsigned)f2bf(of[8 * i + 7] * rs) << 16);
    op4[i] = o;
  }
}

// ---------------------------------------------------------------------------
// 3x3 conv as implicit GEMM (K = 9 taps x 256 ci) + attn add + bias -> sum bf16.
// grid = (2 m-blocks, Nc/128 n-blocks), XCD-swizzled. OOB neighbors -> zero page.
// ---------------------------------------------------------------------------
__global__ __launch_bounds__(256) void conv_gemm(
    const unsigned short* __restrict__ w2b, const unsigned short* __restrict__ vbuf,
    const unsigned short* __restrict__ attnb, const float* __restrict__ lbias,
    const unsigned short* __restrict__ zp, unsigned short* __restrict__ sumb)
{
  __shared__ __align__(16) unsigned short As[128 * 64];
  __shared__ __align__(16) unsigned short Bs[128 * 64];
  const int tid = threadIdx.x;
  const int lane = tid & 63;
  const int wave = tid >> 6;
  const int l15 = lane & 15;
  const int quad = lane >> 4;
  const int wm = (wave >> 1) * 64;
  const int wn = (wave & 1) * 64;
  const int sub = tid & 7;
  const int row0 = tid >> 3;
  int mb, nb;
  xcd_remap(mb, nb);
  const int m0 = mb * 128;
  const int n0 = nb * 128;

  int bi[4], hh[4], ww[4];
#pragma unroll
  for (int it = 0; it < 4; ++it) {
    int n = n0 + it * 32 + row0;
    int b = n >> 14;
    int r = n & 16383;
    int Xw = r >> 10;
    int r2 = r & 1023;
    int Yw = r2 >> 6;
    int t2 = r2 & 63;
    bi[it] = b;
    hh[it] = Xw * 8 + (t2 >> 3);
    ww[it] = Yw * 8 + (t2 & 7);
  }

  f32x4 acc[4][4];
  f32x4 zero = {0.f, 0.f, 0.f, 0.f};
#pragma unroll
  for (int i = 0; i < 4; ++i)
#pragma unroll
    for (int j = 0; j < 4; ++j) acc[i][j] = zero;

  for (int tap = 0; tap < 9; ++tap) {
    const int dy = tap / 3 - 1;
    const int dx = tap - (tap / 3) * 3 - 1;
    const unsigned short* bp[4];
    int bstep[4];
#pragma unroll
    for (int it = 0; it < 4; ++it) {
      int h2 = hh[it] + dy, w2 = ww[it] + dx;
      bool ok = ((unsigned)h2 < 128u) && ((unsigned)w2 < 128u);
      int nn = ((bi[it] * 16 + (h2 >> 3)) * 16 + (w2 >> 3)) * 64 + (h2 & 7) * 8 + (w2 & 7);
      bp[it] = ok ? (vbuf + (size_t)nn * 256 + sub * 8) : (zp + sub * 8);
      bstep[it] = ok ? 64 : 0;
    }
    for (int cc = 0; cc < 4; ++cc) {
#pragma unroll
      for (int it = 0; it < 4; ++it) {
        cp16(As + (size_t)(it * 256 + wave * 64) * 8,
             w2b + ((size_t)(m0 + it * 32 + row0) * 9 + tap) * 256 + cc * 64 + sub * 8);
        cp16(Bs + (size_t)(it * 256 + wave * 64) * 8, bp[it] + cc * bstep[it]);
      }
      __syncthreads();
      mfma_tile(As, Bs, wm, wn, l15, quad, acc);
      __syncthreads();
    }
  }

#pragma unroll
  for (int i = 0; i < 4; ++i) {
    const int ch = m0 + wm + i * 16 + quad * 4;
    const float b0 = lbias[ch + 0], b1 = lbias[ch + 1], b2 = lbias[ch + 2], b3 = lbias[ch + 3];
#pragma unroll
    for (int j = 0; j < 4; ++j) {
      const int n = n0 + wn + j * 16 + l15;
      const unsigned* ap = (const unsigned*)(attnb + (size_t)n * 256 + ch);
      unsigned a0 = ap[0], a1 = ap[1];
      float r0 = acc[i][j][0] + b0 + bf2f((unsigned short)(a0 & 0xffff));
      float r1 = acc[i][j][1] + b1 + bf2f((unsigned short)(a0 >> 16));
      float r2 = acc[i][j][2] + b2 + bf2f((unsigned short)(a1 & 0xffff));
      float r3 = acc[i][j][3] + b3 + bf2f((unsigned short)(a1 >> 16));
      unsigned long long pk = (unsigned long long)f2bf(r0) |
                              ((unsigned long long)f2bf(r1) << 16) |
                              ((unsigned long long)f2bf(r2) << 32) |
                              ((unsigned long long)f2bf(r3) << 48);
      *(unsigned long long*)(sumb + (size_t)n * 256 + ch) = pk;
    }
  }
}

// ---------------------------------------------------------------------------
// Output projection: out_w[256x256] @ sum[n'][256]^T + out_b -> d_out fp32 NCHW.
// XCD-swizzled grid.
// ---------------------------------------------------------------------------
__global__ __launch_bounds__(256) void out_gemm(
    const unsigned short* __restrict__ woutb, const unsigned short* __restrict__ sumb,
    const float* __restrict__ obias, float* __restrict__ out)
{
  __shared__ __align__(16) unsigned short As[128 * 64];
  __shared__ __align__(16) unsigned short Bs[128 * 64];
  const int tid = threadIdx.x;
  const int lane = tid & 63;
  const int wave = tid >> 6;
  const int l15 = lane & 15;
  const int quad = lane >> 4;
  const int wm = (wave >> 1) * 64;
  const int wn = (wave & 1) * 64;
  const int sub = tid & 7;
  const int row0 = tid >> 3;
  int mb, nb;
  xcd_remap(mb, nb);
  const int m0 = mb * 128;
  const int n0 = nb * 128;

  f32x4 acc[4][4];
  f32x4 zero = {0.f, 0.f, 0.f, 0.f};
#pragma unroll
  for (int i = 0; i < 4; ++i)
#pragma unroll
    for (int j = 0; j < 4; ++j) acc[i][j] = zero;

  for (int kt = 0; kt < 4; ++kt) {
    const int k0 = kt * 64;
#pragma unroll
    for (int it = 0; it < 4; ++it) {
      const int row = it * 32 + row0;
      cp16(As + (size_t)(it * 256 + wave * 64) * 8,
           woutb + (size_t)(m0 + row) * 256 + k0 + sub * 8);
      cp16(Bs + (size_t)(it * 256 + wave * 64) * 8,
           sumb + (size_t)(n0 + row) * 256 + k0 + sub * 8);
    }
    __syncthreads();
    mfma_tile(As, Bs, wm, wn, l15, quad, acc);
    __syncthreads();
  }

  int bb4[4], hw4[4];
#pragma unroll
  for (int j = 0; j < 4; ++j) {
    int n = n0 + wn + j * 16 + l15;
    int b = n >> 14;
    int r = n & 16383;
    int Xw = r >> 10;
    int r2 = r & 1023;
    int Yw = r2 >> 6;
    int t2 = r2 & 63;
    bb4[j] = b;
    hw4[j] = (Xw * 8 + (t2 >> 3)) * 128 + Yw * 8 + (t2 & 7);
  }
#pragma unroll
  for (int i = 0; i < 4; ++i) {
    const int mb2 = m0 + wm + i * 16 + quad * 4;
    const float o0 = obias[mb2 + 0], o1 = obias[mb2 + 1], o2 = obias[mb2 + 2], o3 = obias[mb2 + 3];
#pragma unroll
    for (int j = 0; j < 4; ++j) {
      float* o = out + ((size_t)(bb4[j] * 256 + mb2) << 14) + hw4[j];
      o[0] = acc[i][j][0] + o0;
      o[(size_t)1 << 14] = acc[i][j][1] + o1;
      o[(size_t)2 << 14] = acc[i][j][2] + o2;
      o[(size_t)3 << 14] = acc[i][j][3] + o3;
    }
  }
}

// ---------------------------------------------------------------------------
extern "C" void kernel_launch(void* const* d_in, const int* in_sizes, int n_in,
                              void* d_out, int out_size, void* d_ws, size_t ws_size,
                              hipStream_t stream)
{
  const float* x  = (const float*)d_in[0];
  const float* g  = (const float*)d_in[1];
  const float* bb = (const float*)d_in[2];
  const float* wq = (const float*)d_in[3];
  const float* wk = (const float*)d_in[4];
  const float* wv = (const float*)d_in[5];
  const float* lw = (const float*)d_in[6];
  const float* lb = (const float*)d_in[7];
  const float* ow = (const float*)d_in[8];
  const float* ob = (const float*)d_in[9];
  float* out = (float*)d_out;

  char* ws = (char*)d_ws;
  unsigned short* wqkvb = (unsigned short*)(ws + 0);        // 393216 B
  unsigned short* w2b   = (unsigned short*)(ws + 393216);   // 1179648 B
  unsigned short* woutb = (unsigned short*)(ws + 1572864);  // 131072 B
  unsigned short* zp    = (unsigned short*)(ws + 1703936);  // 256 B
  const size_t BUF0 = 1704192;

  // images per chunk, sized to ws (4 bf16 buffers of nimg*16384*256 elems)
  int nimg = 16;
  while (nimg > 1 && BUF0 + 4ull * (size_t)nimg * 8388608ull > ws_size) nimg >>= 1;
  const size_t bufB = (size_t)nimg * 8388608ull;
  unsigned short* xnb = (unsigned short*)(ws + BUF0);
  unsigned short* qb  = (unsigned short*)(ws + BUF0 + bufB);
  unsigned short* kb  = (unsigned short*)(ws + BUF0 + 2 * bufB);
  unsigned short* vb  = (unsigned short*)(ws + BUF0 + 3 * bufB);
  unsigned short* attnb = xnb;  // xn dead after qkv
  unsigned short* sumb  = qb;   // q dead after attention

  setup_kernel<<<3329, 256, 0, stream>>>(wq, wk, wv, lw, ow, wqkvb, w2b, woutb, zp);

  const int nchunk = 16 / nimg;
  const int Nc = nimg * 16384;
  for (int c = 0; c < nchunk; ++c) {
    const float* xc = x + (size_t)c * nimg * 256 * 16384;
    float* oc = out + (size_t)c * nimg * 256 * 16384;
    ln_kernel<<<Nc / 256, 256, 0, stream>>>(xc, g, bb, xnb);
    qkv_gemm<<<dim3(6, Nc / 128), 256, 0, stream>>>(wqkvb, xnb, qb, kb, vb);
    attn_kernel<<<(Nc / 64) * 4, 128, 0, stream>>>(qb, kb, vb, attnb);
    conv_gemm<<<dim3(2, Nc / 128), 256, 0, stream>>>(w2b, vb, attnb, lb, zp, sumb);
    out_gemm<<<dim3(2, Nc / 128), 256, 0, stream>>>(woutb, sumb, ob, oc);
  }
}

// Round 2
// 1751.107 us; speedup vs baseline: 1.0664x; 1.0664x over previous
//
#include <hip/hip_runtime.h>

typedef __attribute__((ext_vector_type(8))) short short8;
typedef __attribute__((ext_vector_type(4))) float f32x4;
typedef __attribute__((ext_vector_type(2))) _Float16 h2;

#define DEV static __device__ __forceinline__

typedef __attribute__((address_space(1))) void GVoid;
typedef __attribute__((address_space(3))) void LVoid;

DEV unsigned short f2bf(float f) {
  unsigned u = __builtin_bit_cast(unsigned, f);
  u += 0x7fffu + ((u >> 16) & 1u);   // RNE
  return (unsigned short)(u >> 16);
}
DEV float bf2f(unsigned short h) {
  unsigned u = ((unsigned)h) << 16;
  return __builtin_bit_cast(float, u);
}
DEV void cp16(void* lds_uniform_base, const void* gsrc) {
  // async global->LDS, 16B per lane; LDS dest = wave-uniform base + lane*16
  __builtin_amdgcn_global_load_lds((GVoid*)gsrc, (LVoid*)lds_uniform_base, 16, 0, 0);
}
DEV float fdot2(h2 a, h2 b, float c) {
  return __builtin_amdgcn_fdot2(a, b, c, false);
}
DEV h2 bch2(float f) { return __builtin_bit_cast(h2, f); }

// Bijective XCD-chunk swizzle: consecutive logical blocks (which share B-panels)
// land on the same XCD's L2. Requires nwg % 8 == 0 (true for all our grids).
DEV void xcd_remap(int& mb, int& nb) {
  const int gx = gridDim.x;
  const int p = blockIdx.x + gx * blockIdx.y;
  const int nwg = gx * gridDim.y;
  const int q = nwg >> 3;
  const int L = (p & 7) * q + (p >> 3);
  mb = L % gx;
  nb = L / gx;
}

// ---------------------------------------------------------------------------
// Setup: cast weights to bf16 (wqkv concat [768][256], conv perm [co][tap][ci],
// out_w [256][256]) + 256B zero page for conv SAME-padding staging.
// ---------------------------------------------------------------------------
__global__ __launch_bounds__(256) void setup_kernel(
    const float* __restrict__ wq, const float* __restrict__ wk, const float* __restrict__ wv,
    const float* __restrict__ lw, const float* __restrict__ ow,
    unsigned short* __restrict__ wqkvb, unsigned short* __restrict__ w2b,
    unsigned short* __restrict__ woutb, unsigned short* __restrict__ zp)
{
  int i = blockIdx.x * 256 + threadIdx.x;
  if (i < 196608) {
    float f = (i < 65536) ? wq[i] : (i < 131072) ? wk[i - 65536] : wv[i - 131072];
    wqkvb[i] = f2bf(f);
  } else if (i < 786432) {
    int j = i - 196608;
    int co = j / 2304;
    int r = j - co * 2304;
    int tap = r >> 8;
    int ci = r & 255;
    // local_w flat [co][ci][ky][kx] = (co*256+ci)*9 + tap
    w2b[j] = f2bf(lw[(co * 256 + ci) * 9 + tap]);
  } else if (i < 851968) {
    int j = i - 786432;
    woutb[j] = f2bf(ow[j]);
  } else if (i < 852096) {
    zp[i - 851968] = 0;
  }
}

// ---------------------------------------------------------------------------
// ChanLayerNorm -> xn bf16 in window-major layout [n'][256], raster-order reads.
// ---------------------------------------------------------------------------
__global__ __launch_bounds__(256) void ln_kernel(
    const float* __restrict__ x, const float* __restrict__ gw,
    const float* __restrict__ bw, unsigned short* __restrict__ xn)
{
  const int t = threadIdx.x;
  const int p = blockIdx.x * 256 + t;   // raster pixel index within chunk
  const int b = p >> 14;
  const int pix = p & 16383;
  const int h = pix >> 7;
  const int w = pix & 127;
  const float* xp = x + ((size_t)b << 22) + pix;  // b*256*16384 + h*128 + w

  float sum = 0.f, ss = 0.f;
#pragma unroll 8
  for (int c = 0; c < 256; ++c) {
    float f = xp[(size_t)c << 14];
    sum += f;
    ss += f * f;
  }
  float mean = sum * (1.f / 256.f);
  float var = ss * (1.f / 256.f) - mean * mean;
  float inv = rsqrtf(var + 1e-5f);

  // window-major output position
  const int pw = ((b * 16 + (h >> 3)) * 16 + (w >> 3)) * 64 + (h & 7) * 8 + (w & 7);
  unsigned short* op = xn + (size_t)pw * 256;
#pragma unroll 2
  for (int c = 0; c < 256; c += 4) {
    float f0 = xp[(size_t)(c + 0) << 14];
    float f1 = xp[(size_t)(c + 1) << 14];
    float f2 = xp[(size_t)(c + 2) << 14];
    float f3 = xp[(size_t)(c + 3) << 14];
    float v0 = (f0 - mean) * inv * gw[c + 0] + bw[c + 0];
    float v1 = (f1 - mean) * inv * gw[c + 1] + bw[c + 1];
    float v2 = (f2 - mean) * inv * gw[c + 2] + bw[c + 2];
    float v3 = (f3 - mean) * inv * gw[c + 3] + bw[c + 3];
    unsigned long long pk = (unsigned long long)f2bf(v0) |
                            ((unsigned long long)f2bf(v1) << 16) |
                            ((unsigned long long)f2bf(v2) << 32) |
                            ((unsigned long long)f2bf(v3) << 48);
    *(unsigned long long*)(op + c) = pk;
  }
}

// ---------------------------------------------------------------------------
// Shared MFMA inner: 128x128 block tile, BK=64 (two 32-k steps), 4 waves 2x2.
// LDS tiles [row][64] with T2 XOR-swizzle on the 16B slot index:
//   LDS[row][slot] holds global[row][slot ^ (row&7)]  (written via pre-swizzled
//   global source, since global_load_lds dest must stay linear — rule #21).
// Read therefore uses slot' = slot ^ (row&7): 8 lanes/slot at distinct rows =
// conflict-free b128 (was 16-way: all 16 l15-lanes of a quad on one slot).
// ---------------------------------------------------------------------------
DEV void mfma_tile(const unsigned short* As, const unsigned short* Bs,
                   int wm, int wn, int l15, int quad, f32x4 (&acc)[4][4])
{
  const int sx = l15 & 7;
#pragma unroll
  for (int ks = 0; ks < 2; ++ks) {
    const int sl = ((ks * 4 + quad) ^ sx) * 8;
    short8 a[4], b[4];
#pragma unroll
    for (int i = 0; i < 4; ++i)
      a[i] = *(const short8*)(As + (wm + i * 16 + l15) * 64 + sl);
#pragma unroll
    for (int j = 0; j < 4; ++j)
      b[j] = *(const short8*)(Bs + (wn + j * 16 + l15) * 64 + sl);
#pragma unroll
    for (int i = 0; i < 4; ++i)
#pragma unroll
      for (int j = 0; j < 4; ++j)
        acc[i][j] = __builtin_amdgcn_mfma_f32_16x16x32_bf16(a[i], b[j], acc[i][j], 0, 0, 0);
  }
}

// ---------------------------------------------------------------------------
// QKV projection: [768x256] @ xn[Nc x 256]^T -> q,k,v bf16 [n'][256]
// grid = (6 m-blocks, Nc/128 n-blocks), XCD-swizzled
// ---------------------------------------------------------------------------
__global__ __launch_bounds__(256) void qkv_gemm(
    const unsigned short* __restrict__ wqkvb, const unsigned short* __restrict__ xn,
    unsigned short* __restrict__ qb, unsigned short* __restrict__ kb,
    unsigned short* __restrict__ vb)
{
  __shared__ __align__(16) unsigned short As[128 * 64];
  __shared__ __align__(16) unsigned short Bs[128 * 64];
  const int tid = threadIdx.x;
  const int lane = tid & 63;
  const int wave = tid >> 6;
  const int l15 = lane & 15;
  const int quad = lane >> 4;
  const int wm = (wave >> 1) * 64;
  const int wn = (wave & 1) * 64;
  const int sub = tid & 7;
  const int row0 = tid >> 3;
  const int ssub = sub ^ (row0 & 7);   // pre-swizzled global slot
  int mb, nb;
  xcd_remap(mb, nb);
  const int m0 = mb * 128;
  const int n0 = nb * 128;

  f32x4 acc[4][4];
  f32x4 zero = {0.f, 0.f, 0.f, 0.f};
#pragma unroll
  for (int i = 0; i < 4; ++i)
#pragma unroll
    for (int j = 0; j < 4; ++j) acc[i][j] = zero;

  for (int kt = 0; kt < 4; ++kt) {
    const int k0 = kt * 64;
#pragma unroll
    for (int it = 0; it < 4; ++it) {
      const int row = it * 32 + row0;
      cp16(As + (size_t)(it * 256 + wave * 64) * 8,
           wqkvb + (size_t)(m0 + row) * 256 + k0 + ssub * 8);
      cp16(Bs + (size_t)(it * 256 + wave * 64) * 8,
           xn + (size_t)(n0 + row) * 256 + k0 + ssub * 8);
    }
    __syncthreads();
    mfma_tile(As, Bs, wm, wn, l15, quad, acc);
    __syncthreads();
  }

  unsigned short* ob = (m0 < 256) ? qb : (m0 < 512) ? kb : vb;
  const int chb = (m0 & 255) + wm;
#pragma unroll
  for (int i = 0; i < 4; ++i) {
    const int ch = chb + i * 16 + quad * 4;
#pragma unroll
    for (int j = 0; j < 4; ++j) {
      const int n = n0 + wn + j * 16 + l15;
      unsigned long long pk = (unsigned long long)f2bf(acc[i][j][0]) |
                              ((unsigned long long)f2bf(acc[i][j][1]) << 16) |
                              ((unsigned long long)f2bf(acc[i][j][2]) << 32) |
                              ((unsigned long long)f2bf(acc[i][j][3]) << 48);
      *(unsigned long long*)(ob + (size_t)n * 256 + ch) = pk;
    }
  }
}

// ---------------------------------------------------------------------------
// Windowed attention via v_dot2_f32_f16. Block = (window, head-pair), 128 thr.
// Thread = (token, head). K staged [tok][c] as f16 (pairs over c), V staged
// TRANSPOSED [c][tok] as f16 (pairs over j) so PV is also dot2. LDS halved
// vs fp32 version -> 8 blocks/CU.
// ---------------------------------------------------------------------------
__global__ __launch_bounds__(128) void attn_kernel(
    const unsigned short* __restrict__ qb, const unsigned short* __restrict__ kb,
    const unsigned short* __restrict__ vb, unsigned short* __restrict__ attnb)
{
  __shared__ __align__(16) _Float16 ks2[2][64][40];  // 32 used + 8 pad; row 80B (16-aligned)
  __shared__ __align__(16) _Float16 vs2[2][32][64];  // [c][j]; row 128B
  const int tid = threadIdx.x;
  const int tok = tid & 63;
  const int hs = tid >> 6;  // 0..1
  const int win = blockIdx.x >> 2;
  const int head = (blockIdx.x & 3) * 2 + hs;
  const size_t base = (size_t)(win * 64 + tok) * 256 + head * 32;

  h2 q2[16];
  {
    const uint4* qp4 = (const uint4*)(qb + base);
    const uint4* kp4 = (const uint4*)(kb + base);
    const uint4* vp4 = (const uint4*)(vb + base);
#pragma unroll
    for (int i = 0; i < 4; ++i) {
      uint4 u = qp4[i];
      unsigned uu[4] = {u.x, u.y, u.z, u.w};
#pragma unroll
      for (int w = 0; w < 4; ++w) {
        h2 p;
        p.x = (_Float16)bf2f((unsigned short)(uu[w] & 0xffff));
        p.y = (_Float16)bf2f((unsigned short)(uu[w] >> 16));
        q2[i * 4 + w] = p;
      }
    }
#pragma unroll
    for (int i = 0; i < 4; ++i) {
      uint4 u = kp4[i];
      unsigned uu[4] = {u.x, u.y, u.z, u.w};
#pragma unroll
      for (int w = 0; w < 4; ++w) {
        int c = 2 * (i * 4 + w);
        ks2[hs][tok][c + 0] = (_Float16)bf2f((unsigned short)(uu[w] & 0xffff));
        ks2[hs][tok][c + 1] = (_Float16)bf2f((unsigned short)(uu[w] >> 16));
      }
      uint4 v = vp4[i];
      unsigned vv[4] = {v.x, v.y, v.z, v.w};
#pragma unroll
      for (int w = 0; w < 4; ++w) {
        int c = 2 * (i * 4 + w);
        vs2[hs][c + 0][tok] = (_Float16)bf2f((unsigned short)(vv[w] & 0xffff));
        vs2[hs][c + 1][tok] = (_Float16)bf2f((unsigned short)(vv[w] >> 16));
      }
    }
  }
  __syncthreads();

  float dots[64];
#pragma unroll 4
  for (int j = 0; j < 64; ++j) {
    const float4* kr = (const float4*)ks2[hs][j];  // wave-uniform b128 reads
    float d = 0.f;
#pragma unroll
    for (int qq = 0; qq < 4; ++qq) {
      float4 raw = kr[qq];
      d = fdot2(q2[4 * qq + 0], bch2(raw.x), d);
      d = fdot2(q2[4 * qq + 1], bch2(raw.y), d);
      d = fdot2(q2[4 * qq + 2], bch2(raw.z), d);
      d = fdot2(q2[4 * qq + 3], bch2(raw.w), d);
    }
    dots[j] = d * 0.17677669529663688f;  // 32^-0.5
  }
  float mx = -1e30f;
#pragma unroll
  for (int j = 0; j < 64; ++j) mx = fmaxf(mx, dots[j]);
  float s = 0.f;
#pragma unroll
  for (int j = 0; j < 64; ++j) {
    float e = __expf(dots[j] - mx);
    dots[j] = e;
    s += e;
  }
  const float rs = 1.f / s;

  h2 p2[32];
#pragma unroll
  for (int jp = 0; jp < 32; ++jp) {
    h2 p;
    p.x = (_Float16)dots[2 * jp];
    p.y = (_Float16)dots[2 * jp + 1];
    p2[jp] = p;
  }

  float of[32];
#pragma unroll 4
  for (int c = 0; c < 32; ++c) {
    const float4* vr = (const float4*)vs2[hs][c];  // wave-uniform b128 reads
    float o = 0.f;
#pragma unroll
    for (int qq = 0; qq < 8; ++qq) {
      float4 raw = vr[qq];
      o = fdot2(p2[4 * qq + 0], bch2(raw.x), o);
      o = fdot2(p2[4 * qq + 1], bch2(raw.y), o);
      o = fdot2(p2[4 * qq + 2], bch2(raw.z), o);
      o = fdot2(p2[4 * qq + 3], bch2(raw.w), o);
    }
    of[c] = o;
  }

  uint4* op4 = (uint4*)(attnb + base);
#pragma unroll
  for (int i = 0; i < 4; ++i) {
    uint4 o;
    o.x = (unsigned)f2bf(of[8 * i + 0] * rs) | ((unsigned)f2bf(of[8 * i + 1] * rs) << 16);
    o.y = (unsigned)f2bf(of[8 * i + 2] * rs) | ((unsigned)f2bf(of[8 * i + 3] * rs) << 16);
    o.z = (unsigned)f2bf(of[8 * i + 4] * rs) | ((unsigned)f2bf(of[8 * i + 5] * rs) << 16);
    o.w = (unsigned)f2bf(of[8 * i + 6] * rs) | ((unsigned)f2bf(of[8 * i + 7] * rs) << 16);
    op4[i] = o;
  }
}

// ---------------------------------------------------------------------------
// 3x3 conv as implicit GEMM (K = 9 taps x 256 ci) + attn add + bias -> sum bf16.
// grid = (2 m-blocks, Nc/128 n-blocks), XCD-swizzled. OOB neighbors -> zero page.
// ---------------------------------------------------------------------------
__global__ __launch_bounds__(256) void conv_gemm(
    const unsigned short* __restrict__ w2b, const unsigned short* __restrict__ vbuf,
    const unsigned short* __restrict__ attnb, const float* __restrict__ lbias,
    const unsigned short* __restrict__ zp, unsigned short* __restrict__ sumb)
{
  __shared__ __align__(16) unsigned short As[128 * 64];
  __shared__ __align__(16) unsigned short Bs[128 * 64];
  const int tid = threadIdx.x;
  const int lane = tid & 63;
  const int wave = tid >> 6;
  const int l15 = lane & 15;
  const int quad = lane >> 4;
  const int wm = (wave >> 1) * 64;
  const int wn = (wave & 1) * 64;
  const int sub = tid & 7;
  const int row0 = tid >> 3;
  const int ssub = sub ^ (row0 & 7);   // pre-swizzled global slot
  int mb, nb;
  xcd_remap(mb, nb);
  const int m0 = mb * 128;
  const int n0 = nb * 128;

  int bi[4], hh[4], ww[4];
#pragma unroll
  for (int it = 0; it < 4; ++it) {
    int n = n0 + it * 32 + row0;
    int b = n >> 14;
    int r = n & 16383;
    int Xw = r >> 10;
    int r2 = r & 1023;
    int Yw = r2 >> 6;
    int t2 = r2 & 63;
    bi[it] = b;
    hh[it] = Xw * 8 + (t2 >> 3);
    ww[it] = Yw * 8 + (t2 & 7);
  }

  f32x4 acc[4][4];
  f32x4 zero = {0.f, 0.f, 0.f, 0.f};
#pragma unroll
  for (int i = 0; i < 4; ++i)
#pragma unroll
    for (int j = 0; j < 4; ++j) acc[i][j] = zero;

  for (int tap = 0; tap < 9; ++tap) {
    const int dy = tap / 3 - 1;
    const int dx = tap - (tap / 3) * 3 - 1;
    const unsigned short* bp[4];
    int bstep[4];
#pragma unroll
    for (int it = 0; it < 4; ++it) {
      int h2_ = hh[it] + dy, w2_ = ww[it] + dx;
      bool ok = ((unsigned)h2_ < 128u) && ((unsigned)w2_ < 128u);
      int nn = ((bi[it] * 16 + (h2_ >> 3)) * 16 + (w2_ >> 3)) * 64 + (h2_ & 7) * 8 + (w2_ & 7);
      bp[it] = ok ? (vbuf + (size_t)nn * 256 + ssub * 8) : (zp + ssub * 8);
      bstep[it] = ok ? 64 : 0;
    }
    for (int cc = 0; cc < 4; ++cc) {
#pragma unroll
      for (int it = 0; it < 4; ++it) {
        cp16(As + (size_t)(it * 256 + wave * 64) * 8,
             w2b + ((size_t)(m0 + it * 32 + row0) * 9 + tap) * 256 + cc * 64 + ssub * 8);
        cp16(Bs + (size_t)(it * 256 + wave * 64) * 8, bp[it] + cc * bstep[it]);
      }
      __syncthreads();
      mfma_tile(As, Bs, wm, wn, l15, quad, acc);
      __syncthreads();
    }
  }

#pragma unroll
  for (int i = 0; i < 4; ++i) {
    const int ch = m0 + wm + i * 16 + quad * 4;
    const float b0 = lbias[ch + 0], b1 = lbias[ch + 1], b2 = lbias[ch + 2], b3 = lbias[ch + 3];
#pragma unroll
    for (int j = 0; j < 4; ++j) {
      const int n = n0 + wn + j * 16 + l15;
      const unsigned* ap = (const unsigned*)(attnb + (size_t)n * 256 + ch);
      unsigned a0 = ap[0], a1 = ap[1];
      float r0 = acc[i][j][0] + b0 + bf2f((unsigned short)(a0 & 0xffff));
      float r1 = acc[i][j][1] + b1 + bf2f((unsigned short)(a0 >> 16));
      float r2 = acc[i][j][2] + b2 + bf2f((unsigned short)(a1 & 0xffff));
      float r3 = acc[i][j][3] + b3 + bf2f((unsigned short)(a1 >> 16));
      unsigned long long pk = (unsigned long long)f2bf(r0) |
                              ((unsigned long long)f2bf(r1) << 16) |
                              ((unsigned long long)f2bf(r2) << 32) |
                              ((unsigned long long)f2bf(r3) << 48);
      *(unsigned long long*)(sumb + (size_t)n * 256 + ch) = pk;
    }
  }
}

// ---------------------------------------------------------------------------
// Output projection: out_w[256x256] @ sum[n'][256]^T + out_b -> d_out fp32 NCHW.
// XCD-swizzled grid.
// ---------------------------------------------------------------------------
__global__ __launch_bounds__(256) void out_gemm(
    const unsigned short* __restrict__ woutb, const unsigned short* __restrict__ sumb,
    const float* __restrict__ obias, float* __restrict__ out)
{
  __shared__ __align__(16) unsigned short As[128 * 64];
  __shared__ __align__(16) unsigned short Bs[128 * 64];
  const int tid = threadIdx.x;
  const int lane = tid & 63;
  const int wave = tid >> 6;
  const int l15 = lane & 15;
  const int quad = lane >> 4;
  const int wm = (wave >> 1) * 64;
  const int wn = (wave & 1) * 64;
  const int sub = tid & 7;
  const int row0 = tid >> 3;
  const int ssub = sub ^ (row0 & 7);   // pre-swizzled global slot
  int mb, nb;
  xcd_remap(mb, nb);
  const int m0 = mb * 128;
  const int n0 = nb * 128;

  f32x4 acc[4][4];
  f32x4 zero = {0.f, 0.f, 0.f, 0.f};
#pragma unroll
  for (int i = 0; i < 4; ++i)
#pragma unroll
    for (int j = 0; j < 4; ++j) acc[i][j] = zero;

  for (int kt = 0; kt < 4; ++kt) {
    const int k0 = kt * 64;
#pragma unroll
    for (int it = 0; it < 4; ++it) {
      const int row = it * 32 + row0;
      cp16(As + (size_t)(it * 256 + wave * 64) * 8,
           woutb + (size_t)(m0 + row) * 256 + k0 + ssub * 8);
      cp16(Bs + (size_t)(it * 256 + wave * 64) * 8,
           sumb + (size_t)(n0 + row) * 256 + k0 + ssub * 8);
    }
    __syncthreads();
    mfma_tile(As, Bs, wm, wn, l15, quad, acc);
    __syncthreads();
  }

  int bb4[4], hw4[4];
#pragma unroll
  for (int j = 0; j < 4; ++j) {
    int n = n0 + wn + j * 16 + l15;
    int b = n >> 14;
    int r = n & 16383;
    int Xw = r >> 10;
    int r2 = r & 1023;
    int Yw = r2 >> 6;
    int t2 = r2 & 63;
    bb4[j] = b;
    hw4[j] = (Xw * 8 + (t2 >> 3)) * 128 + Yw * 8 + (t2 & 7);
  }
#pragma unroll
  for (int i = 0; i < 4; ++i) {
    const int mb2 = m0 + wm + i * 16 + quad * 4;
    const float o0 = obias[mb2 + 0], o1 = obias[mb2 + 1], o2 = obias[mb2 + 2], o3 = obias[mb2 + 3];
#pragma unroll
    for (int j = 0; j < 4; ++j) {
      float* o = out + ((size_t)(bb4[j] * 256 + mb2) << 14) + hw4[j];
      o[0] = acc[i][j][0] + o0;
      o[(size_t)1 << 14] = acc[i][j][1] + o1;
      o[(size_t)2 << 14] = acc[i][j][2] + o2;
      o[(size_t)3 << 14] = acc[i][j][3] + o3;
    }
  }
}

// ---------------------------------------------------------------------------
extern "C" void kernel_launch(void* const* d_in, const int* in_sizes, int n_in,
                              void* d_out, int out_size, void* d_ws, size_t ws_size,
                              hipStream_t stream)
{
  const float* x  = (const float*)d_in[0];
  const float* g  = (const float*)d_in[1];
  const float* bb = (const float*)d_in[2];
  const float* wq = (const float*)d_in[3];
  const float* wk = (const float*)d_in[4];
  const float* wv = (const float*)d_in[5];
  const float* lw = (const float*)d_in[6];
  const float* lb = (const float*)d_in[7];
  const float* ow = (const float*)d_in[8];
  const float* ob = (const float*)d_in[9];
  float* out = (float*)d_out;

  char* ws = (char*)d_ws;
  unsigned short* wqkvb = (unsigned short*)(ws + 0);        // 393216 B
  unsigned short* w2b   = (unsigned short*)(ws + 393216);   // 1179648 B
  unsigned short* woutb = (unsigned short*)(ws + 1572864);  // 131072 B
  unsigned short* zp    = (unsigned short*)(ws + 1703936);  // 256 B
  const size_t BUF0 = 1704192;

  // images per chunk, sized to ws (4 bf16 buffers of nimg*16384*256 elems)
  int nimg = 16;
  while (nimg > 1 && BUF0 + 4ull * (size_t)nimg * 8388608ull > ws_size) nimg >>= 1;
  const size_t bufB = (size_t)nimg * 8388608ull;
  unsigned short* xnb = (unsigned short*)(ws + BUF0);
  unsigned short* qb  = (unsigned short*)(ws + BUF0 + bufB);
  unsigned short* kb  = (unsigned short*)(ws + BUF0 + 2 * bufB);
  unsigned short* vb  = (unsigned short*)(ws + BUF0 + 3 * bufB);
  unsigned short* attnb = xnb;  // xn dead after qkv
  unsigned short* sumb  = qb;   // q dead after attention

  setup_kernel<<<3329, 256, 0, stream>>>(wq, wk, wv, lw, ow, wqkvb, w2b, woutb, zp);

  const int nchunk = 16 / nimg;
  const int Nc = nimg * 16384;
  for (int c = 0; c < nchunk; ++c) {
    const float* xc = x + (size_t)c * nimg * 256 * 16384;
    float* oc = out + (size_t)c * nimg * 256 * 16384;
    ln_kernel<<<Nc / 256, 256, 0, stream>>>(xc, g, bb, xnb);
    qkv_gemm<<<dim3(6, Nc / 128), 256, 0, stream>>>(wqkvb, xnb, qb, kb, vb);
    attn_kernel<<<(Nc / 64) * 4, 128, 0, stream>>>(qb, kb, vb, attnb);
    conv_gemm<<<dim3(2, Nc / 128), 256, 0, stream>>>(w2b, vb, attnb, lb, zp, sumb);
    out_gemm<<<dim3(2, Nc / 128), 256, 0, stream>>>(woutb, sumb, ob, oc);
  }
}

// Round 3
// 1497.321 us; speedup vs baseline: 1.2472x; 1.1695x over previous
//
#include <hip/hip_runtime.h>

typedef __attribute__((ext_vector_type(8))) short short8;
typedef __attribute__((ext_vector_type(4))) float f32x4;
typedef __attribute__((ext_vector_type(2))) _Float16 h2;
typedef __attribute__((ext_vector_type(8))) _Float16 h8;

#define DEV static __device__ __forceinline__

typedef __attribute__((address_space(1))) void GVoid;
typedef __attribute__((address_space(3))) void LVoid;

DEV unsigned short f2h(float f) {
  _Float16 h = (_Float16)f;          // RNE
  return __builtin_bit_cast(unsigned short, h);
}
DEV float h2f(unsigned short u) {
  return (float)__builtin_bit_cast(_Float16, u);
}
DEV unsigned pkh(float a, float b) {
  h2 h;
  h.x = (_Float16)a;
  h.y = (_Float16)b;
  return __builtin_bit_cast(unsigned, h);
}
DEV void cp16(void* lds_uniform_base, const void* gsrc) {
  // async global->LDS, 16B per lane; LDS dest = wave-uniform base + lane*16
  __builtin_amdgcn_global_load_lds((GVoid*)gsrc, (LVoid*)lds_uniform_base, 16, 0, 0);
}
DEV float fdot2(h2 a, h2 b, float c) {
  return __builtin_amdgcn_fdot2(a, b, c, false);
}

// Bijective XCD-chunk swizzle: consecutive logical blocks (which share B-panels)
// land on the same XCD's L2. Requires nwg % 8 == 0 (true for all our grids).
DEV void xcd_remap(int& mb, int& nb) {
  const int gx = gridDim.x;
  const int p = blockIdx.x + gx * blockIdx.y;
  const int nwg = gx * gridDim.y;
  const int q = nwg >> 3;
  const int L = (p & 7) * q + (p >> 3);
  mb = L % gx;
  nb = L / gx;
}

// ---------------------------------------------------------------------------
// Setup: cast weights to f16 (wqkv concat [768][256], conv perm [co][tap][ci],
// out_w [256][256]) + 256B zero page for conv SAME-padding staging.
// ---------------------------------------------------------------------------
__global__ __launch_bounds__(256) void setup_kernel(
    const float* __restrict__ wq, const float* __restrict__ wk, const float* __restrict__ wv,
    const float* __restrict__ lw, const float* __restrict__ ow,
    unsigned short* __restrict__ wqkvb, unsigned short* __restrict__ w2b,
    unsigned short* __restrict__ woutb, unsigned short* __restrict__ zp)
{
  int i = blockIdx.x * 256 + threadIdx.x;
  if (i < 196608) {
    float f = (i < 65536) ? wq[i] : (i < 131072) ? wk[i - 65536] : wv[i - 131072];
    wqkvb[i] = f2h(f);
  } else if (i < 786432) {
    int j = i - 196608;
    int co = j / 2304;
    int r = j - co * 2304;
    int tap = r >> 8;
    int ci = r & 255;
    // local_w flat [co][ci][ky][kx] = (co*256+ci)*9 + tap
    w2b[j] = f2h(lw[(co * 256 + ci) * 9 + tap]);
  } else if (i < 851968) {
    int j = i - 786432;
    woutb[j] = f2h(ow[j]);
  } else if (i < 852096) {
    zp[i - 851968] = 0;
  }
}

// ---------------------------------------------------------------------------
// ChanLayerNorm -> xn f16 in window-major layout [n'][256], raster-order reads.
// ---------------------------------------------------------------------------
__global__ __launch_bounds__(256) void ln_kernel(
    const float* __restrict__ x, const float* __restrict__ gw,
    const float* __restrict__ bw, unsigned short* __restrict__ xn)
{
  const int t = threadIdx.x;
  const int p = blockIdx.x * 256 + t;   // raster pixel index within chunk
  const int b = p >> 14;
  const int pix = p & 16383;
  const int h = pix >> 7;
  const int w = pix & 127;
  const float* xp = x + ((size_t)b << 22) + pix;  // b*256*16384 + h*128 + w

  float sum = 0.f, ss = 0.f;
#pragma unroll 8
  for (int c = 0; c < 256; ++c) {
    float f = xp[(size_t)c << 14];
    sum += f;
    ss += f * f;
  }
  float mean = sum * (1.f / 256.f);
  float var = ss * (1.f / 256.f) - mean * mean;
  float inv = rsqrtf(var + 1e-5f);

  // window-major output position
  const int pw = ((b * 16 + (h >> 3)) * 16 + (w >> 3)) * 64 + (h & 7) * 8 + (w & 7);
  unsigned short* op = xn + (size_t)pw * 256;
#pragma unroll 2
  for (int c = 0; c < 256; c += 4) {
    float f0 = xp[(size_t)(c + 0) << 14];
    float f1 = xp[(size_t)(c + 1) << 14];
    float f2 = xp[(size_t)(c + 2) << 14];
    float f3 = xp[(size_t)(c + 3) << 14];
    float v0 = (f0 - mean) * inv * gw[c + 0] + bw[c + 0];
    float v1 = (f1 - mean) * inv * gw[c + 1] + bw[c + 1];
    float v2 = (f2 - mean) * inv * gw[c + 2] + bw[c + 2];
    float v3 = (f3 - mean) * inv * gw[c + 3] + bw[c + 3];
    unsigned long long pk = (unsigned long long)pkh(v0, v1) |
                            ((unsigned long long)pkh(v2, v3) << 32);
    *(unsigned long long*)(op + c) = pk;
  }
}

// ---------------------------------------------------------------------------
// Shared MFMA inner (f16): 128x128 block tile, BK=64 (two 32-k steps), 4 waves.
// LDS tiles [row][64] with T2 XOR-swizzle on the 16B slot index (rule #21:
// linear LDS dest, pre-swizzled global src, same involution on ds_read).
// ---------------------------------------------------------------------------
DEV void mfma_tile(const unsigned short* As, const unsigned short* Bs,
                   int wm, int wn, int l15, int quad, f32x4 (&acc)[4][4])
{
  const int sx = l15 & 7;
#pragma unroll
  for (int ks = 0; ks < 2; ++ks) {
    const int sl = ((ks * 4 + quad) ^ sx) * 8;
    short8 a[4], b[4];
#pragma unroll
    for (int i = 0; i < 4; ++i)
      a[i] = *(const short8*)(As + (wm + i * 16 + l15) * 64 + sl);
#pragma unroll
    for (int j = 0; j < 4; ++j)
      b[j] = *(const short8*)(Bs + (wn + j * 16 + l15) * 64 + sl);
#pragma unroll
    for (int i = 0; i < 4; ++i)
#pragma unroll
      for (int j = 0; j < 4; ++j)
        acc[i][j] = __builtin_amdgcn_mfma_f32_16x16x32_f16(
            __builtin_bit_cast(h8, a[i]), __builtin_bit_cast(h8, b[j]), acc[i][j], 0, 0, 0);
  }
}

// ---------------------------------------------------------------------------
// QKV projection: [768x256] @ xn[Nc x 256]^T -> q,k,v f16 [n'][256]
// grid = (6 m-blocks, Nc/128 n-blocks), XCD-swizzled
// ---------------------------------------------------------------------------
__global__ __launch_bounds__(256) void qkv_gemm(
    const unsigned short* __restrict__ wqkvb, const unsigned short* __restrict__ xn,
    unsigned short* __restrict__ qb, unsigned short* __restrict__ kb,
    unsigned short* __restrict__ vb)
{
  __shared__ __align__(16) unsigned short As[128 * 64];
  __shared__ __align__(16) unsigned short Bs[128 * 64];
  const int tid = threadIdx.x;
  const int lane = tid & 63;
  const int wave = tid >> 6;
  const int l15 = lane & 15;
  const int quad = lane >> 4;
  const int wm = (wave >> 1) * 64;
  const int wn = (wave & 1) * 64;
  const int sub = tid & 7;
  const int row0 = tid >> 3;
  const int ssub = sub ^ (row0 & 7);   // pre-swizzled global slot
  int mb, nb;
  xcd_remap(mb, nb);
  const int m0 = mb * 128;
  const int n0 = nb * 128;

  f32x4 acc[4][4];
  f32x4 zero = {0.f, 0.f, 0.f, 0.f};
#pragma unroll
  for (int i = 0; i < 4; ++i)
#pragma unroll
    for (int j = 0; j < 4; ++j) acc[i][j] = zero;

  for (int kt = 0; kt < 4; ++kt) {
    const int k0 = kt * 64;
#pragma unroll
    for (int it = 0; it < 4; ++it) {
      const int row = it * 32 + row0;
      cp16(As + (size_t)(it * 256 + wave * 64) * 8,
           wqkvb + (size_t)(m0 + row) * 256 + k0 + ssub * 8);
      cp16(Bs + (size_t)(it * 256 + wave * 64) * 8,
           xn + (size_t)(n0 + row) * 256 + k0 + ssub * 8);
    }
    __syncthreads();
    mfma_tile(As, Bs, wm, wn, l15, quad, acc);
    __syncthreads();
  }

  unsigned short* ob = (m0 < 256) ? qb : (m0 < 512) ? kb : vb;
  const int chb = (m0 & 255) + wm;
#pragma unroll
  for (int i = 0; i < 4; ++i) {
    const int ch = chb + i * 16 + quad * 4;
#pragma unroll
    for (int j = 0; j < 4; ++j) {
      const int n = n0 + wn + j * 16 + l15;
      unsigned long long pk = (unsigned long long)pkh(acc[i][j][0], acc[i][j][1]) |
                              ((unsigned long long)pkh(acc[i][j][2], acc[i][j][3]) << 32);
      *(unsigned long long*)(ob + (size_t)n * 256 + ch) = pk;
    }
  }
}

// ---------------------------------------------------------------------------
// Windowed attention via v_dot2_f32_f16, conversion-free (q/k/v stored f16).
// Block = (window, head-pair), 128 thr. Thread = (token, head). K staged
// [tok][c] (pairs over c), V staged TRANSPOSED [c][tok] (pairs over j).
// ALL per-thread arrays fully unrolled -> registers (rule #20).
// ---------------------------------------------------------------------------
__global__ __launch_bounds__(128) void attn_kernel(
    const unsigned short* __restrict__ qb, const unsigned short* __restrict__ kb,
    const unsigned short* __restrict__ vb, unsigned short* __restrict__ attnb)
{
  __shared__ __align__(16) _Float16 ks2[2][64][40];  // 32 used + 8 pad; row 80B
  __shared__ __align__(16) _Float16 vs2[2][32][64];  // [c][j]; row 128B
  const int tid = threadIdx.x;
  const int tok = tid & 63;
  const int hs = tid >> 6;  // 0..1, wave-uniform
  const int win = blockIdx.x >> 2;
  const int head = (blockIdx.x & 3) * 2 + hs;
  const size_t base = (size_t)(win * 64 + tok) * 256 + head * 32;

  h2 q2[16];
  {
    const uint4* qp4 = (const uint4*)(qb + base);
    const uint4* kp4 = (const uint4*)(kb + base);
    const uint4* vp4 = (const uint4*)(vb + base);
    const _Float16 sc = (_Float16)0.17677669529663688f;  // 32^-0.5 folded into q
    h2 sc2;
    sc2.x = sc;
    sc2.y = sc;
#pragma unroll
    for (int i = 0; i < 4; ++i) {
      uint4 u = qp4[i];
      q2[i * 4 + 0] = __builtin_bit_cast(h2, u.x) * sc2;
      q2[i * 4 + 1] = __builtin_bit_cast(h2, u.y) * sc2;
      q2[i * 4 + 2] = __builtin_bit_cast(h2, u.z) * sc2;
      q2[i * 4 + 3] = __builtin_bit_cast(h2, u.w) * sc2;
      // K row: raw byte copy, no conversion
      *(uint4*)&ks2[hs][tok][8 * i] = kp4[i];
      // V transposed scatter (2-way bank alias on b16 stores = free)
      uint4 v = vp4[i];
      unsigned vv[4] = {v.x, v.y, v.z, v.w};
#pragma unroll
      for (int w = 0; w < 4; ++w) {
        h2 hv = __builtin_bit_cast(h2, vv[w]);
        int c = 2 * (i * 4 + w);
        vs2[hs][c + 0][tok] = hv.x;
        vs2[hs][c + 1][tok] = hv.y;
      }
    }
  }
  __syncthreads();

  float dots[64];
#pragma unroll
  for (int j = 0; j < 64; ++j) {
    const uint4* kr = (const uint4*)ks2[hs][j];  // wave-uniform b128 broadcast
    float d = 0.f;
#pragma unroll
    for (int qq = 0; qq < 4; ++qq) {
      uint4 raw = kr[qq];
      d = fdot2(q2[4 * qq + 0], __builtin_bit_cast(h2, raw.x), d);
      d = fdot2(q2[4 * qq + 1], __builtin_bit_cast(h2, raw.y), d);
      d = fdot2(q2[4 * qq + 2], __builtin_bit_cast(h2, raw.z), d);
      d = fdot2(q2[4 * qq + 3], __builtin_bit_cast(h2, raw.w), d);
    }
    dots[j] = d;
  }
  float mx = -1e30f;
#pragma unroll
  for (int j = 0; j < 64; ++j) mx = fmaxf(mx, dots[j]);
  float s = 0.f;
#pragma unroll
  for (int j = 0; j < 64; ++j) {
    float e = __expf(dots[j] - mx);
    dots[j] = e;
    s += e;
  }
  const float rs = 1.f / s;

  h2 p2[32];
#pragma unroll
  for (int jp = 0; jp < 32; ++jp) {
    h2 p;
    p.x = (_Float16)dots[2 * jp];
    p.y = (_Float16)dots[2 * jp + 1];
    p2[jp] = p;
  }

  float of[32];
#pragma unroll
  for (int c = 0; c < 32; ++c) {
    const uint4* vr = (const uint4*)vs2[hs][c];  // wave-uniform b128 broadcast
    float o = 0.f;
#pragma unroll
    for (int qq = 0; qq < 8; ++qq) {
      uint4 raw = vr[qq];
      o = fdot2(p2[4 * qq + 0], __builtin_bit_cast(h2, raw.x), o);
      o = fdot2(p2[4 * qq + 1], __builtin_bit_cast(h2, raw.y), o);
      o = fdot2(p2[4 * qq + 2], __builtin_bit_cast(h2, raw.z), o);
      o = fdot2(p2[4 * qq + 3], __builtin_bit_cast(h2, raw.w), o);
    }
    of[c] = o;
  }

  uint4* op4 = (uint4*)(attnb + base);
#pragma unroll
  for (int i = 0; i < 4; ++i) {
    uint4 o;
    o.x = pkh(of[8 * i + 0] * rs, of[8 * i + 1] * rs);
    o.y = pkh(of[8 * i + 2] * rs, of[8 * i + 3] * rs);
    o.z = pkh(of[8 * i + 4] * rs, of[8 * i + 5] * rs);
    o.w = pkh(of[8 * i + 6] * rs, of[8 * i + 7] * rs);
    op4[i] = o;
  }
}

// ---------------------------------------------------------------------------
// 3x3 conv as implicit GEMM (K = 9 taps x 256 ci) + attn add + bias -> sum f16.
// grid = (2 m-blocks, Nc/128 n-blocks), XCD-swizzled. OOB neighbors -> zero page.
// ---------------------------------------------------------------------------
__global__ __launch_bounds__(256) void conv_gemm(
    const unsigned short* __restrict__ w2b, const unsigned short* __restrict__ vbuf,
    const unsigned short* __restrict__ attnb, const float* __restrict__ lbias,
    const unsigned short* __restrict__ zp, unsigned short* __restrict__ sumb)
{
  __shared__ __align__(16) unsigned short As[128 * 64];
  __shared__ __align__(16) unsigned short Bs[128 * 64];
  const int tid = threadIdx.x;
  const int lane = tid & 63;
  const int wave = tid >> 6;
  const int l15 = lane & 15;
  const int quad = lane >> 4;
  const int wm = (wave >> 1) * 64;
  const int wn = (wave & 1) * 64;
  const int sub = tid & 7;
  const int row0 = tid >> 3;
  const int ssub = sub ^ (row0 & 7);   // pre-swizzled global slot
  int mb, nb;
  xcd_remap(mb, nb);
  const int m0 = mb * 128;
  const int n0 = nb * 128;

  int bi[4], hh[4], ww[4];
#pragma unroll
  for (int it = 0; it < 4; ++it) {
    int n = n0 + it * 32 + row0;
    int b = n >> 14;
    int r = n & 16383;
    int Xw = r >> 10;
    int r2 = r & 1023;
    int Yw = r2 >> 6;
    int t2 = r2 & 63;
    bi[it] = b;
    hh[it] = Xw * 8 + (t2 >> 3);
    ww[it] = Yw * 8 + (t2 & 7);
  }

  f32x4 acc[4][4];
  f32x4 zero = {0.f, 0.f, 0.f, 0.f};
#pragma unroll
  for (int i = 0; i < 4; ++i)
#pragma unroll
    for (int j = 0; j < 4; ++j) acc[i][j] = zero;

  for (int tap = 0; tap < 9; ++tap) {
    const int dy = tap / 3 - 1;
    const int dx = tap - (tap / 3) * 3 - 1;
    const unsigned short* bp[4];
    int bstep[4];
#pragma unroll
    for (int it = 0; it < 4; ++it) {
      int h2_ = hh[it] + dy, w2_ = ww[it] + dx;
      bool ok = ((unsigned)h2_ < 128u) && ((unsigned)w2_ < 128u);
      int nn = ((bi[it] * 16 + (h2_ >> 3)) * 16 + (w2_ >> 3)) * 64 + (h2_ & 7) * 8 + (w2_ & 7);
      bp[it] = ok ? (vbuf + (size_t)nn * 256 + ssub * 8) : (zp + ssub * 8);
      bstep[it] = ok ? 64 : 0;
    }
    for (int cc = 0; cc < 4; ++cc) {
#pragma unroll
      for (int it = 0; it < 4; ++it) {
        cp16(As + (size_t)(it * 256 + wave * 64) * 8,
             w2b + ((size_t)(m0 + it * 32 + row0) * 9 + tap) * 256 + cc * 64 + ssub * 8);
        cp16(Bs + (size_t)(it * 256 + wave * 64) * 8, bp[it] + cc * bstep[it]);
      }
      __syncthreads();
      mfma_tile(As, Bs, wm, wn, l15, quad, acc);
      __syncthreads();
    }
  }

#pragma unroll
  for (int i = 0; i < 4; ++i) {
    const int ch = m0 + wm + i * 16 + quad * 4;
    const float b0 = lbias[ch + 0], b1 = lbias[ch + 1], b2 = lbias[ch + 2], b3 = lbias[ch + 3];
#pragma unroll
    for (int j = 0; j < 4; ++j) {
      const int n = n0 + wn + j * 16 + l15;
      const unsigned* ap = (const unsigned*)(attnb + (size_t)n * 256 + ch);
      unsigned a0 = ap[0], a1 = ap[1];
      float r0 = acc[i][j][0] + b0 + h2f((unsigned short)(a0 & 0xffff));
      float r1 = acc[i][j][1] + b1 + h2f((unsigned short)(a0 >> 16));
      float r2 = acc[i][j][2] + b2 + h2f((unsigned short)(a1 & 0xffff));
      float r3 = acc[i][j][3] + b3 + h2f((unsigned short)(a1 >> 16));
      unsigned long long pk = (unsigned long long)pkh(r0, r1) |
                              ((unsigned long long)pkh(r2, r3) << 32);
      *(unsigned long long*)(sumb + (size_t)n * 256 + ch) = pk;
    }
  }
}

// ---------------------------------------------------------------------------
// Output projection: out_w[256x256] @ sum[n'][256]^T + out_b -> d_out fp32 NCHW.
// XCD-swizzled grid.
// ---------------------------------------------------------------------------
__global__ __launch_bounds__(256) void out_gemm(
    const unsigned short* __restrict__ woutb, const unsigned short* __restrict__ sumb,
    const float* __restrict__ obias, float* __restrict__ out)
{
  __shared__ __align__(16) unsigned short As[128 * 64];
  __shared__ __align__(16) unsigned short Bs[128 * 64];
  const int tid = threadIdx.x;
  const int lane = tid & 63;
  const int wave = tid >> 6;
  const int l15 = lane & 15;
  const int quad = lane >> 4;
  const int wm = (wave >> 1) * 64;
  const int wn = (wave & 1) * 64;
  const int sub = tid & 7;
  const int row0 = tid >> 3;
  const int ssub = sub ^ (row0 & 7);   // pre-swizzled global slot
  int mb, nb;
  xcd_remap(mb, nb);
  const int m0 = mb * 128;
  const int n0 = nb * 128;

  f32x4 acc[4][4];
  f32x4 zero = {0.f, 0.f, 0.f, 0.f};
#pragma unroll
  for (int i = 0; i < 4; ++i)
#pragma unroll
    for (int j = 0; j < 4; ++j) acc[i][j] = zero;

  for (int kt = 0; kt < 4; ++kt) {
    const int k0 = kt * 64;
#pragma unroll
    for (int it = 0; it < 4; ++it) {
      const int row = it * 32 + row0;
      cp16(As + (size_t)(it * 256 + wave * 64) * 8,
           woutb + (size_t)(m0 + row) * 256 + k0 + ssub * 8);
      cp16(Bs + (size_t)(it * 256 + wave * 64) * 8,
           sumb + (size_t)(n0 + row) * 256 + k0 + ssub * 8);
    }
    __syncthreads();
    mfma_tile(As, Bs, wm, wn, l15, quad, acc);
    __syncthreads();
  }

  int bb4[4], hw4[4];
#pragma unroll
  for (int j = 0; j < 4; ++j) {
    int n = n0 + wn + j * 16 + l15;
    int b = n >> 14;
    int r = n & 16383;
    int Xw = r >> 10;
    int r2 = r & 1023;
    int Yw = r2 >> 6;
    int t2 = r2 & 63;
    bb4[j] = b;
    hw4[j] = (Xw * 8 + (t2 >> 3)) * 128 + Yw * 8 + (t2 & 7);
  }
#pragma unroll
  for (int i = 0; i < 4; ++i) {
    const int mb2 = m0 + wm + i * 16 + quad * 4;
    const float o0 = obias[mb2 + 0], o1 = obias[mb2 + 1], o2 = obias[mb2 + 2], o3 = obias[mb2 + 3];
#pragma unroll
    for (int j = 0; j < 4; ++j) {
      float* o = out + ((size_t)(bb4[j] * 256 + mb2) << 14) + hw4[j];
      o[0] = acc[i][j][0] + o0;
      o[(size_t)1 << 14] = acc[i][j][1] + o1;
      o[(size_t)2 << 14] = acc[i][j][2] + o2;
      o[(size_t)3 << 14] = acc[i][j][3] + o3;
    }
  }
}

// ---------------------------------------------------------------------------
extern "C" void kernel_launch(void* const* d_in, const int* in_sizes, int n_in,
                              void* d_out, int out_size, void* d_ws, size_t ws_size,
                              hipStream_t stream)
{
  const float* x  = (const float*)d_in[0];
  const float* g  = (const float*)d_in[1];
  const float* bb = (const float*)d_in[2];
  const float* wq = (const float*)d_in[3];
  const float* wk = (const float*)d_in[4];
  const float* wv = (const float*)d_in[5];
  const float* lw = (const float*)d_in[6];
  const float* lb = (const float*)d_in[7];
  const float* ow = (const float*)d_in[8];
  const float* ob = (const float*)d_in[9];
  float* out = (float*)d_out;

  char* ws = (char*)d_ws;
  unsigned short* wqkvb = (unsigned short*)(ws + 0);        // 393216 B
  unsigned short* w2b   = (unsigned short*)(ws + 393216);   // 1179648 B
  unsigned short* woutb = (unsigned short*)(ws + 1572864);  // 131072 B
  unsigned short* zp    = (unsigned short*)(ws + 1703936);  // 256 B
  const size_t BUF0 = 1704192;

  // images per chunk, sized to ws (4 f16 buffers of nimg*16384*256 elems)
  int nimg = 16;
  while (nimg > 1 && BUF0 + 4ull * (size_t)nimg * 8388608ull > ws_size) nimg >>= 1;
  const size_t bufB = (size_t)nimg * 8388608ull;
  unsigned short* xnb = (unsigned short*)(ws + BUF0);
  unsigned short* qb  = (unsigned short*)(ws + BUF0 + bufB);
  unsigned short* kb  = (unsigned short*)(ws + BUF0 + 2 * bufB);
  unsigned short* vb  = (unsigned short*)(ws + BUF0 + 3 * bufB);
  unsigned short* attnb = xnb;  // xn dead after qkv
  unsigned short* sumb  = qb;   // q dead after attention

  setup_kernel<<<3329, 256, 0, stream>>>(wq, wk, wv, lw, ow, wqkvb, w2b, woutb, zp);

  const int nchunk = 16 / nimg;
  const int Nc = nimg * 16384;
  for (int c = 0; c < nchunk; ++c) {
    const float* xc = x + (size_t)c * nimg * 256 * 16384;
    float* oc = out + (size_t)c * nimg * 256 * 16384;
    ln_kernel<<<Nc / 256, 256, 0, stream>>>(xc, g, bb, xnb);
    qkv_gemm<<<dim3(6, Nc / 128), 256, 0, stream>>>(wqkvb, xnb, qb, kb, vb);
    attn_kernel<<<(Nc / 64) * 4, 128, 0, stream>>>(qb, kb, vb, attnb);
    conv_gemm<<<dim3(2, Nc / 128), 256, 0, stream>>>(w2b, vb, attnb, lb, zp, sumb);
    out_gemm<<<dim3(2, Nc / 128), 256, 0, stream>>>(woutb, sumb, ob, oc);
  }
}